// Round 10
// baseline (14822.887 us; speedup 1.0000x reference)
//
#include <hip/hip_runtime.h>
#include <cfloat>
#include <cmath>

#define Bn 128
#define Tn 512
#define En 256
#define Hn 512
#define NTAGS 32

// ws float offsets
#define OFF_HF 0                          // [2][512][128] fwd h ([k][b])
#define OFF_HB 131072
#define OFF_CF 262144                     // [512][128]
#define OFF_CB 327680
#define OFF_EF 393216                     // [512][32][128]
#define OFF_EB 2490368
#define OFF_WTG 4587520                   // [2][768][2048] W transposed, c' = h*4+gate
// end 7733248 floats = 29.5 MB

__global__ __launch_bounds__(512) void transpose_w_k(
    const float* __restrict__ Wih_f, const float* __restrict__ Whh_f,
    const float* __restrict__ Wih_b, const float* __restrict__ Whh_b,
    float* __restrict__ ws)
{
  const int dir = blockIdx.x >> 10;
  const int k   = blockIdx.x & 1023;
  if (k >= 768) return;
  const float* Whh = dir ? Whh_b : Whh_f;
  const float* Wih = dir ? Wih_b : Wih_f;
  float* outr = ws + OFF_WTG + ((size_t)dir * 768 + k) * 2048;
  #pragma unroll
  for (int i = 0; i < 4; ++i) {
    const int cp = threadIdx.x + i * 512;      // c' = h*4 + gate
    const int h = cp >> 2;
    const int g = cp & 3;
    outr[cp] = (k < Hn) ? Whh[(size_t)(g * Hn + h) * Hn + k]
                        : Wih[(size_t)(g * Hn + h) * En + (k - Hn)];
  }
}

__global__ __launch_bounds__(512, 2) void lstm_step_k(
    const float* __restrict__ X, const float* __restrict__ masks,
    const float* __restrict__ bias_f, const float* __restrict__ bias_b,
    const float* __restrict__ Wout, float* __restrict__ ws, int s)
{
  __shared__ __align__(16) float P[8 * 16 * 128];  // 64 KB k-split partials [kq][n][b]
  __shared__ __align__(16) float GL[128 * 17];     // 8.7 KB gates [b][n]
  __shared__ __align__(16) float RS[8 * 128];      // 4 KB emission partials [kq][b]

  const int tid  = threadIdx.x;
  const int blk  = blockIdx.x;
  const int lane = tid & 63;
  const int kq   = __builtin_amdgcn_readfirstlane(tid >> 6);  // wave 0..7 = k-octile
  const int b0   = lane * 2;                                  // thread's b pair

  const int dir = blk >> 7;
  const int bbk = blk & 127;
  const int t = dir ? (Tn - 1 - s) : s;
  const float* bias = dir ? bias_b : bias_f;
  float* hbuf = ws + (dir ? OFF_HB : OFF_HF);
  float* cbuf = ws + (dir ? OFF_CB : OFF_CF);
  const float* hprev = hbuf + ((s + 1) & 1) * (Hn * Bn);
  float*       hnext = hbuf + (s & 1) * (Hn * Bn);
  const int hidx0 = bbk * 4;
  const int etag  = bbk & 31;
  const int ebq   = bbk >> 5;

  // ---- epilogue preloads ----
  const int pb  = tid & 127;
  const int phh = tid >> 7;                     // 0..3
  const int hidxp = hidx0 + phh;
  const float mval = masks[(size_t)pb * Tn + t];
  const float bi  = bias[hidxp];
  const float bf_ = bias[Hn + hidxp];
  const float bg_ = bias[2 * Hn + hidxp];
  const float bo_ = bias[3 * Hn + hidxp];
  const float cold = cbuf[hidxp * Bn + pb];
  const float hold = hprev[hidxp * Bn + pb];

  // wave-uniform W base (scalar path) and emission row
  const float* WT  = ws + OFF_WTG + (size_t)dir * (768 * 2048) + hidx0 * 4;
  const float* wox = Wout + (size_t)etag * (2 * Hn) + dir * Hn;

  float acc[2][16];
  #pragma unroll
  for (int m = 0; m < 2; ++m)
    #pragma unroll
    for (int n = 0; n < 16; ++n) acc[m][n] = 0.f;
  float eac[2] = {0.f, 0.f};

  // ---- h-part: k = 0..511 (this wave: 8 k per 64-chunk) ----
  #pragma unroll 2
  for (int c = 0; c < 8; ++c) {
    const int kb = c * 64 + kq * 8;
    #pragma unroll
    for (int j = 0; j < 8; ++j) {
      const int k = kb + j;
      const float2 a  = *(const float2*)&hprev[(size_t)k * Bn + b0];
      const float4 w0 = *(const float4*)(WT + (size_t)k * 2048);
      const float4 w1 = *(const float4*)(WT + (size_t)k * 2048 + 4);
      const float4 w2 = *(const float4*)(WT + (size_t)k * 2048 + 8);
      const float4 w3 = *(const float4*)(WT + (size_t)k * 2048 + 12);
      const float wo = wox[k];
      const float w_[16] = {w0.x, w0.y, w0.z, w0.w, w1.x, w1.y, w1.z, w1.w,
                            w2.x, w2.y, w2.z, w2.w, w3.x, w3.y, w3.z, w3.w};
      #pragma unroll
      for (int n = 0; n < 16; ++n) {
        acc[0][n] += a.x * w_[n];
        acc[1][n] += a.y * w_[n];
      }
      eac[0] += a.x * wo;
      eac[1] += a.y * wo;
    }
  }

  // ---- x-part: e = 0..255 (k = 512..767) ----
  const size_t xrow0 = (size_t)b0 * (Tn * En) + (size_t)t * En;
  const size_t xrow1 = xrow0 + (size_t)(Tn * En);
  #pragma unroll 1
  for (int c = 0; c < 4; ++c) {
    const int e0 = c * 64 + kq * 8;
    const float4 xa0 = *(const float4*)&X[xrow0 + e0];
    const float4 xa1 = *(const float4*)&X[xrow0 + e0 + 4];
    const float4 xb0 = *(const float4*)&X[xrow1 + e0];
    const float4 xb1 = *(const float4*)&X[xrow1 + e0 + 4];
    const float x0[8] = {xa0.x, xa0.y, xa0.z, xa0.w, xa1.x, xa1.y, xa1.z, xa1.w};
    const float x1[8] = {xb0.x, xb0.y, xb0.z, xb0.w, xb1.x, xb1.y, xb1.z, xb1.w};
    #pragma unroll
    for (int j = 0; j < 8; ++j) {
      const int k = 512 + e0 + j;
      const float4 w0 = *(const float4*)(WT + (size_t)k * 2048);
      const float4 w1 = *(const float4*)(WT + (size_t)k * 2048 + 4);
      const float4 w2 = *(const float4*)(WT + (size_t)k * 2048 + 8);
      const float4 w3 = *(const float4*)(WT + (size_t)k * 2048 + 12);
      const float w_[16] = {w0.x, w0.y, w0.z, w0.w, w1.x, w1.y, w1.z, w1.w,
                            w2.x, w2.y, w2.z, w2.w, w3.x, w3.y, w3.z, w3.w};
      #pragma unroll
      for (int n = 0; n < 16; ++n) {
        acc[0][n] += x0[j] * w_[n];
        acc[1][n] += x1[j] * w_[n];
      }
    }
  }

  // ---- k-split (8-way over waves) reduction via LDS ----
  #pragma unroll
  for (int n = 0; n < 16; ++n)
    *(float2*)&P[(kq * 16 + n) * 128 + b0] = make_float2(acc[0][n], acc[1][n]);
  *(float2*)&RS[kq * 128 + b0] = make_float2(eac[0], eac[1]);
  __syncthreads();
  {
    const int b  = tid & 127;
    const int nq = tid >> 7;                    // 0..3
    #pragma unroll
    for (int nn = 0; nn < 4; ++nn) {
      const int n = nq * 4 + nn;
      float v = 0.f;
      #pragma unroll
      for (int k2 = 0; k2 < 8; ++k2)
        v += P[(k2 * 16 + n) * 128 + b];
      GL[b * 17 + n] = v;
    }
  }
  // emission finish (RS complete since the barrier above)
  if (s > 0 && tid < 32) {
    const int tprev = dir ? (Tn - s) : (s - 1);
    float* Edst = ws + (dir ? OFF_EB : OFF_EF);
    float v = 0.f;
    #pragma unroll
    for (int g = 0; g < 8; ++g) v += RS[g * 128 + ebq * 32 + tid];
    Edst[(size_t)tprev * (NTAGS * Bn) + etag * Bn + ebq * 32 + tid] = v;
  }
  __syncthreads();

  // ---- LSTM pointwise update: n = phh*4 + gate ----
  {
    const float gi = GL[pb * 17 + phh * 4 + 0] + bi;
    const float gf = GL[pb * 17 + phh * 4 + 1] + bf_;
    const float gc = GL[pb * 17 + phh * 4 + 2] + bg_;
    const float go = GL[pb * 17 + phh * 4 + 3] + bo_;
    const float iv = 1.f / (1.f + expf(-gi));
    const float fv = 1.f / (1.f + expf(-gf));
    const float gv = tanhf(gc);
    const float ov = 1.f / (1.f + expf(-go));
    const float cnew = fv * cold + iv * gv;
    const float hnew = ov * tanhf(cnew);
    hnext[hidxp * Bn + pb] = (mval > 0.f) ? hnew : hold;
    cbuf[hidxp * Bn + pb]  = (mval > 0.f) ? cnew : cold;
  }
}

__global__ __launch_bounds__(512) void emis_final_k(const float* __restrict__ Wout,
                                                    float* __restrict__ ws)
{
  __shared__ float RSf[16 * Bn];
  const int tid = threadIdx.x;
  const int dir = blockIdx.x >> 5;
  const int tag = blockIdx.x & 31;
  // final states: h_f[T-1] and h_b[0] both written at s=511 (buf 1)
  const float* hsrc = ws + (dir ? OFF_HB : OFF_HF) + 1 * (Hn * Bn);
  const int tprev = dir ? 0 : (Tn - 1);
  const float* wrow = Wout + (size_t)tag * (2 * Hn) + dir * Hn;
  float* Edst = ws + (dir ? OFF_EB : OFF_EF);
  const int bq = tid & 31;
  const int kg = tid >> 5;
  float4 a4 = make_float4(0.f, 0.f, 0.f, 0.f);
  #pragma unroll 4
  for (int kk = 0; kk < 32; ++kk) {
    const int k = kg * 32 + kk;
    const float w = wrow[k];
    const float4 h4 = *(const float4*)&hsrc[k * Bn + bq * 4];
    a4.x += h4.x * w; a4.y += h4.y * w; a4.z += h4.z * w; a4.w += h4.w * w;
  }
  *(float4*)&RSf[kg * Bn + bq * 4] = a4;
  __syncthreads();
  if (tid < 128) {
    float v = 0.f;
    #pragma unroll
    for (int g = 0; g < 16; ++g) v += RSf[g * Bn + tid];
    Edst[(size_t)tprev * (NTAGS * Bn) + tag * Bn + tid] = v;
  }
}

__global__ __launch_bounds__(64) void viterbi_k(
    const float* __restrict__ Ef, const float* __restrict__ Eb,
    const float* __restrict__ bout, const float* __restrict__ trans,
    const float* __restrict__ masks, float* __restrict__ out)
{
  const int b = blockIdx.x;
  const int l = threadIdx.x;
  __shared__ float tr[32][32];
  __shared__ float al[32];
  __shared__ float msk[512];
  __shared__ unsigned char bp[512][32];
  __shared__ int tseq[512];

  for (int i = l; i < 1024; i += 64) tr[i >> 5][i & 31] = trans[i];
  for (int i = l; i < 512; i += 64) msk[i] = masks[(size_t)b * 512 + i];
  __syncthreads();

  const int j  = l & 31;
  const int hi = l >> 5;
  if (l < 32)
    al[j] = Ef[(size_t)j * Bn + b] + Eb[(size_t)j * Bn + b] + bout[j] + tr[30][j];
  __syncthreads();

  for (int t = 1; t < 512; ++t) {
    float pmax = -FLT_MAX; int pidx = 0;
    #pragma unroll
    for (int ii = 0; ii < 16; ++ii) {
      const int i = hi * 16 + ii;
      const float sc = al[i] + tr[i][j];
      if (sc > pmax) { pmax = sc; pidx = i; }   // strict > => first occurrence
    }
    const float omax = __shfl_down(pmax, 32);
    const int   oidx = __shfl_down(pidx, 32);
    if (l < 32) {
      if (omax > pmax) { pmax = omax; pidx = oidx; } // high half only on strict >
      bp[t][j] = (unsigned char)pidx;
      const float e = Ef[(size_t)t * (NTAGS * Bn) + j * Bn + b]
                    + Eb[(size_t)t * (NTAGS * Bn) + j * Bn + b] + bout[j];
      const float na = pmax + e;
      if (msk[t] > 0.f) al[j] = na;
    }
    __syncthreads();
  }

  float fv; int fidx;
  if (l < 32) { fv = al[l] + tr[l][31]; fidx = l; }
  else        { fv = -FLT_MAX; fidx = 1 << 30; }
  #pragma unroll
  for (int off = 16; off >= 1; off >>= 1) {
    const float v2 = __shfl_xor(fv, off);
    const int   i2 = __shfl_xor(fidx, off);
    if (v2 > fv || (v2 == fv && i2 < fidx)) { fv = v2; fidx = i2; }
  }
  if (l == 0) {
    out[b] = fv;
    int cur = fidx;
    tseq[511] = cur;
    for (int t = 511; t >= 1; --t) {
      const int prev = (msk[t] > 0.f) ? (int)bp[t][cur] : cur;
      tseq[t - 1] = prev;
      cur = prev;
    }
  }
  __syncthreads();
  for (int t = l; t < 512; t += 64) {
    const float tv = (msk[t] > 0.f) ? (float)tseq[t] : -1.0f;
    out[Bn + (size_t)b * 512 + t] = tv;
  }
}

extern "C" void kernel_launch(void* const* d_in, const int* in_sizes, int n_in,
                              void* d_out, int out_size, void* d_ws, size_t ws_size,
                              hipStream_t stream) {
  const float* X      = (const float*)d_in[0];
  const float* masks  = (const float*)d_in[1];
  const float* Wih_f  = (const float*)d_in[3];
  const float* Whh_f  = (const float*)d_in[4];
  const float* bf     = (const float*)d_in[5];
  const float* Wih_b  = (const float*)d_in[6];
  const float* Whh_b  = (const float*)d_in[7];
  const float* bb     = (const float*)d_in[8];
  const float* Wout   = (const float*)d_in[9];
  const float* bout   = (const float*)d_in[10];
  const float* trans  = (const float*)d_in[11];
  float* ws  = (float*)d_ws;
  float* out = (float*)d_out;

  // zero h/c state region (graph replays re-run this)
  hipMemsetAsync(d_ws, 0, (size_t)OFF_EF * sizeof(float), stream);

  // one-time (per replay) W transpose into ws
  transpose_w_k<<<2048, 512, 0, stream>>>(Wih_f, Whh_f, Wih_b, Whh_b, ws);

  for (int s = 0; s < Tn; ++s)
    lstm_step_k<<<256, 512, 0, stream>>>(X, masks, bf, bb, Wout, ws, s);
  emis_final_k<<<64, 512, 0, stream>>>(Wout, ws);
  viterbi_k<<<128, 64, 0, stream>>>(ws + OFF_EF, ws + OFF_EB, bout, trans, masks, out);
}

// Round 11
// 12220.464 us; speedup vs baseline: 1.2130x; 1.2130x over previous
//
#include <hip/hip_runtime.h>
#include <cfloat>
#include <cmath>

#define Bn 128
#define Tn 512
#define En 256
#define Hn 512
#define NTAGS 32
#define CHK 64                   // k-rows per staged chunk
#define NCHK 12                  // 8 h-chunks (512 k) + 4 x-chunks (256 k)

// ws float offsets (h stored [k][b] dense)
#define OFF_HF 0                          // [2][512][128]
#define OFF_HB 131072
#define OFF_CF 262144                     // [512][128]
#define OFF_CB 327680
#define OFF_EF 393216                     // [512][32][128]
#define OFF_EB 2490368
// end 4587520 floats = 17.5 MB

__device__ __forceinline__ void gll16(const float* g, float* l) {
  __builtin_amdgcn_global_load_lds(
      (const __attribute__((address_space(1))) void*)g,
      (__attribute__((address_space(3))) void*)l, 16, 0, 0);
}

__global__ __launch_bounds__(512, 2) void lstm_step_k(
    const float* __restrict__ X, const float* __restrict__ masks,
    const float* __restrict__ Wih_f, const float* __restrict__ Whh_f, const float* __restrict__ bias_f,
    const float* __restrict__ Wih_b, const float* __restrict__ Whh_b, const float* __restrict__ bias_b,
    const float* __restrict__ Wout, float* __restrict__ ws, int s)
{
  __shared__ __align__(16) float WT[768 * 16];      // 48 KB  W [k][c]
  __shared__ __align__(16) float HX[2][CHK * Bn];   // 64 KB  A chunks [k][b] dense
  __shared__ __align__(16) float GL[Bn * 17];       // 8.7 KB gates [b][c]
  __shared__ __align__(16) float WoL[512];          // 2 KB   Wout row (block's tag/dir)
  __shared__ __align__(16) float RS[8 * Bn];        // 4 KB   emission partials [slice][b]

  const int tid  = threadIdx.x;
  const int blk  = blockIdx.x;
  const int lane = tid & 63;
  const int wid  = __builtin_amdgcn_readfirstlane(tid >> 6);  // 0..7 uniform
  const int bq   = tid & 15;         // b-quad pair: bA = bq*4, bB = 64 + bq*4
  const int cg   = (tid >> 4) & 1;   // c half: cols [cg*8, cg*8+8)
  const int ks   = tid >> 5;         // 0..15 k-slice: k in [ks*4, ks*4+4) per chunk

  const int dir = blk >> 7;
  const int bbk = blk & 127;
  const int t = dir ? (Tn - 1 - s) : s;
  const float* Wih  = dir ? Wih_b  : Wih_f;
  const float* Whh  = dir ? Whh_b  : Whh_f;
  const float* bias = dir ? bias_b : bias_f;
  float* hbuf = ws + (dir ? OFF_HB : OFF_HF);
  float* cbuf = ws + (dir ? OFF_CB : OFF_CF);
  const int rbuf = (s + 1) & 1;
  const int wbuf = s & 1;
  const float* hprev = hbuf + rbuf * (Hn * Bn);
  float*       hnext = hbuf + wbuf * (Hn * Bn);
  const int hidx0 = bbk * 4;

  // emission role: (dir, tag); ebq==0 blocks write the full 128-b row
  const int etag = bbk & 31;
  const int ebq  = bbk >> 5;

  // ---- prologue: issue chunk-0 staging (gll16), then stage W + WoL ----
  #pragma unroll
  for (int r = 0; r < 4; ++r) {
    const int item = r * 512 + tid;                // 2048 float4 = 64x128
    gll16(hprev + item * 4, &HX[0][item * 4]);
  }
  {
    const int lc = tid & 15;
    const int kw = tid >> 4;                       // 0..31
    const int row = (lc >> 2) * Hn + hidx0 + (lc & 3);
    #pragma unroll
    for (int i = 0; i < 6; ++i) {
      const int k = (kw + i * 32) * 4;             // 0..764
      float4 w4;
      if (k < Hn) w4 = *(const float4*)&Whh[(size_t)row * Hn + k];
      else        w4 = *(const float4*)&Wih[(size_t)row * En + (k - Hn)];
      WT[(k + 0) * 16 + lc] = w4.x; WT[(k + 1) * 16 + lc] = w4.y;
      WT[(k + 2) * 16 + lc] = w4.z; WT[(k + 3) * 16 + lc] = w4.w;
    }
  }
  if (tid < 128) {
    const float4 wo = *(const float4*)&Wout[(size_t)etag * (2 * Hn) + dir * Hn + tid * 4];
    *(float4*)&WoL[tid * 4] = wo;
  }
  __syncthreads();

  float acc[8][8];
  #pragma unroll
  for (int m = 0; m < 8; ++m)
    #pragma unroll
    for (int n = 0; n < 8; ++n) acc[m][n] = 0.f;
  float eac[8] = {0.f, 0.f, 0.f, 0.f, 0.f, 0.f, 0.f, 0.f};

  const int xbq = tid & 127;                       // for x staging
  const int xeg = tid >> 7;                        // 0..3

  // ---- main loop: 12 chunks of 64 k (c 0..7 = h via gll16, c 8..11 = x via regs) ----
  #pragma unroll 1
  for (int c = 0; c < NCHK; ++c) {
    const int nxt = c + 1;
    float4 st[4];
    if (nxt < 8) {
      const float* src = hprev + nxt * (CHK * Bn);
      float* dst = &HX[nxt & 1][0];
      #pragma unroll
      for (int r = 0; r < 4; ++r) {
        const int item = r * 512 + tid;
        gll16(src + item * 4, dst + item * 4);
      }
    } else if (nxt < NCHK) {
      const int e0 = (nxt - 8) * CHK;
      #pragma unroll
      for (int r = 0; r < 4; ++r)
        st[r] = *(const float4*)&X[(size_t)xbq * (Tn * En) + (size_t)t * En + e0 + xeg * 16 + r * 4];
    }

    // ---- compute chunk c: 8x8 per-lane tile, 4 b128 per 64 FMA ----
    {
      const float* HXc = &HX[c & 1][0];
      #pragma unroll
      for (int j = 0; j < 4; ++j) {
        const int kl = ks * 4 + j;
        const int kg = c * 64 + kl;
        const float4 a0 = *(const float4*)&HXc[kl * Bn + bq * 4];
        const float4 a1 = *(const float4*)&HXc[kl * Bn + 64 + bq * 4];
        const float4 w0 = *(const float4*)&WT[kg * 16 + cg * 8];
        const float4 w1 = *(const float4*)&WT[kg * 16 + cg * 8 + 4];
        const float a_[8] = {a0.x, a0.y, a0.z, a0.w, a1.x, a1.y, a1.z, a1.w};
        const float w_[8] = {w0.x, w0.y, w0.z, w0.w, w1.x, w1.y, w1.z, w1.w};
        #pragma unroll
        for (int m = 0; m < 8; ++m)
          #pragma unroll
          for (int n = 0; n < 8; ++n)
            acc[m][n] += a_[m] * w_[n];
        if (c < 8) {
          const float wo = WoL[kg];
          #pragma unroll
          for (int m = 0; m < 8; ++m) eac[m] += a_[m] * wo;
        }
      }
    }

    // ---- write staged x regs into next buffer ----
    if (nxt >= 8 && nxt < NCHK) {
      float* dst = &HX[nxt & 1][0];
      #pragma unroll
      for (int r = 0; r < 4; ++r) {
        const int el = xeg * 16 + r * 4;
        dst[(el + 0) * Bn + xbq] = st[r].x;
        dst[(el + 1) * Bn + xbq] = st[r].y;
        dst[(el + 2) * Bn + xbq] = st[r].z;
        dst[(el + 3) * Bn + xbq] = st[r].w;
      }
    }
    __syncthreads();
  }

  // ---- fold ks pairs in-register (lane ^ 32), leaving 8 slices = wid ----
  #pragma unroll
  for (int m = 0; m < 8; ++m)
    #pragma unroll
    for (int n = 0; n < 8; ++n)
      acc[m][n] += __shfl_xor(acc[m][n], 32);
  #pragma unroll
  for (int m = 0; m < 8; ++m) eac[m] += __shfl_xor(eac[m], 32);

  // ---- slice reduction via LDS: P[wid][c16][b128] overlaid on HX ----
  float* P = &HX[0][0];                            // 16384 floats
  if ((lane >> 5) == 0) {
    #pragma unroll
    for (int n = 0; n < 8; ++n) {
      *(float4*)&P[wid * 2048 + (cg * 8 + n) * Bn + bq * 4] =
          make_float4(acc[0][n], acc[1][n], acc[2][n], acc[3][n]);
      *(float4*)&P[wid * 2048 + (cg * 8 + n) * Bn + 64 + bq * 4] =
          make_float4(acc[4][n], acc[5][n], acc[6][n], acc[7][n]);
    }
    if (cg == 0) {
      *(float4*)&RS[wid * Bn + bq * 4] = make_float4(eac[0], eac[1], eac[2], eac[3]);
      *(float4*)&RS[wid * Bn + 64 + bq * 4] = make_float4(eac[4], eac[5], eac[6], eac[7]);
    }
  }
  __syncthreads();
  {
    const int b  = tid & 127;
    const int cq = tid >> 7;                       // 0..3
    #pragma unroll
    for (int nn = 0; nn < 4; ++nn) {
      const int n = cq * 4 + nn;
      float v = 0.f;
      #pragma unroll
      for (int k2 = 0; k2 < 8; ++k2)
        v += P[k2 * 2048 + n * Bn + b];
      GL[b * 17 + n] = v;
    }
  }
  // emission finish: full 128-b row for this block's tag (ebq==0 blocks only)
  if (s > 0 && ebq == 0 && tid < 128) {
    const int tprev = dir ? (Tn - s) : (s - 1);
    float* Edst = ws + (dir ? OFF_EB : OFF_EF);
    float v = 0.f;
    #pragma unroll
    for (int g = 0; g < 8; ++g) v += RS[g * Bn + tid];
    Edst[(size_t)tprev * (NTAGS * Bn) + etag * Bn + tid] = v;
  }
  __syncthreads();

  // ---- LSTM pointwise update ----
  {
    const int b  = tid & 127;
    const int hh = tid >> 7;
    const int hidx = hidx0 + hh;
    const float gi = GL[b * 17 + hh]      + bias[hidx];
    const float gf = GL[b * 17 + 4 + hh]  + bias[Hn + hidx];
    const float gc = GL[b * 17 + 8 + hh]  + bias[2 * Hn + hidx];
    const float go = GL[b * 17 + 12 + hh] + bias[3 * Hn + hidx];
    const float iv = 1.f / (1.f + expf(-gi));
    const float fv = 1.f / (1.f + expf(-gf));
    const float gv = tanhf(gc);
    const float ov = 1.f / (1.f + expf(-go));
    const float cold = cbuf[hidx * Bn + b];
    const float cnew = fv * cold + iv * gv;
    const float hold = hprev[hidx * Bn + b];
    const float hnew = ov * tanhf(cnew);
    const float m = masks[(size_t)b * Tn + t];
    hnext[hidx * Bn + b] = (m > 0.f) ? hnew : hold;
    cbuf[hidx * Bn + b]  = (m > 0.f) ? cnew : cold;
  }
}

__global__ __launch_bounds__(512) void emis_final_k(const float* __restrict__ Wout,
                                                    float* __restrict__ ws)
{
  __shared__ float RSf[16 * Bn];
  const int tid = threadIdx.x;
  const int dir = blockIdx.x >> 5;
  const int tag = blockIdx.x & 31;
  // final states: h_f[T-1] and h_b[0] both written at s=511 (wbuf=1)
  const float* hsrc = ws + (dir ? OFF_HB : OFF_HF) + 1 * (Hn * Bn);
  const int tprev = dir ? 0 : (Tn - 1);
  const float* wrow = Wout + (size_t)tag * (2 * Hn) + dir * Hn;
  float* Edst = ws + (dir ? OFF_EB : OFF_EF);
  const int bq = tid & 31;
  const int kg = tid >> 5;
  float4 a4 = make_float4(0.f, 0.f, 0.f, 0.f);
  #pragma unroll 4
  for (int kk = 0; kk < 32; ++kk) {
    const int k = kg * 32 + kk;
    const float w = wrow[k];
    const float4 h4 = *(const float4*)&hsrc[k * Bn + bq * 4];
    a4.x += h4.x * w; a4.y += h4.y * w; a4.z += h4.z * w; a4.w += h4.w * w;
  }
  *(float4*)&RSf[kg * Bn + bq * 4] = a4;
  __syncthreads();
  if (tid < 128) {
    float v = 0.f;
    #pragma unroll
    for (int g = 0; g < 16; ++g) v += RSf[g * Bn + tid];
    Edst[(size_t)tprev * (NTAGS * Bn) + tag * Bn + tid] = v;
  }
}

__global__ __launch_bounds__(64) void viterbi_k(
    const float* __restrict__ Ef, const float* __restrict__ Eb,
    const float* __restrict__ bout, const float* __restrict__ trans,
    const float* __restrict__ masks, float* __restrict__ out)
{
  const int b = blockIdx.x;
  const int l = threadIdx.x;
  __shared__ float tr[32][32];
  __shared__ float al[32];
  __shared__ float msk[512];
  __shared__ unsigned char bp[512][32];
  __shared__ int tseq[512];

  for (int i = l; i < 1024; i += 64) tr[i >> 5][i & 31] = trans[i];
  for (int i = l; i < 512; i += 64) msk[i] = masks[(size_t)b * 512 + i];
  __syncthreads();

  const int j  = l & 31;
  const int hi = l >> 5;
  if (l < 32)
    al[j] = Ef[(size_t)j * Bn + b] + Eb[(size_t)j * Bn + b] + bout[j] + tr[30][j];
  __syncthreads();

  for (int t = 1; t < 512; ++t) {
    float pmax = -FLT_MAX; int pidx = 0;
    #pragma unroll
    for (int ii = 0; ii < 16; ++ii) {
      const int i = hi * 16 + ii;
      const float sc = al[i] + tr[i][j];
      if (sc > pmax) { pmax = sc; pidx = i; }   // strict > => first occurrence
    }
    const float omax = __shfl_down(pmax, 32);
    const int   oidx = __shfl_down(pidx, 32);
    if (l < 32) {
      if (omax > pmax) { pmax = omax; pidx = oidx; } // high half only on strict >
      bp[t][j] = (unsigned char)pidx;
      const float e = Ef[(size_t)t * (NTAGS * Bn) + j * Bn + b]
                    + Eb[(size_t)t * (NTAGS * Bn) + j * Bn + b] + bout[j];
      const float na = pmax + e;
      if (msk[t] > 0.f) al[j] = na;
    }
    __syncthreads();
  }

  float fv; int fidx;
  if (l < 32) { fv = al[l] + tr[l][31]; fidx = l; }
  else        { fv = -FLT_MAX; fidx = 1 << 30; }
  #pragma unroll
  for (int off = 16; off >= 1; off >>= 1) {
    const float v2 = __shfl_xor(fv, off);
    const int   i2 = __shfl_xor(fidx, off);
    if (v2 > fv || (v2 == fv && i2 < fidx)) { fv = v2; fidx = i2; }
  }
  if (l == 0) {
    out[b] = fv;
    int cur = fidx;
    tseq[511] = cur;
    for (int t = 511; t >= 1; --t) {
      const int prev = (msk[t] > 0.f) ? (int)bp[t][cur] : cur;
      tseq[t - 1] = prev;
      cur = prev;
    }
  }
  __syncthreads();
  for (int t = l; t < 512; t += 64) {
    const float tv = (msk[t] > 0.f) ? (float)tseq[t] : -1.0f;
    out[Bn + (size_t)b * 512 + t] = tv;
  }
}

extern "C" void kernel_launch(void* const* d_in, const int* in_sizes, int n_in,
                              void* d_out, int out_size, void* d_ws, size_t ws_size,
                              hipStream_t stream) {
  const float* X      = (const float*)d_in[0];
  const float* masks  = (const float*)d_in[1];
  const float* Wih_f  = (const float*)d_in[3];
  const float* Whh_f  = (const float*)d_in[4];
  const float* bf     = (const float*)d_in[5];
  const float* Wih_b  = (const float*)d_in[6];
  const float* Whh_b  = (const float*)d_in[7];
  const float* bb     = (const float*)d_in[8];
  const float* Wout   = (const float*)d_in[9];
  const float* bout   = (const float*)d_in[10];
  const float* trans  = (const float*)d_in[11];
  float* ws  = (float*)d_ws;
  float* out = (float*)d_out;

  // zero h/c state region (graph replays re-run this)
  hipMemsetAsync(d_ws, 0, (size_t)OFF_EF * sizeof(float), stream);

  for (int s = 0; s < Tn; ++s)
    lstm_step_k<<<256, 512, 0, stream>>>(X, masks, Wih_f, Whh_f, bf,
                                         Wih_b, Whh_b, bb, Wout, ws, s);
  emis_final_k<<<64, 512, 0, stream>>>(Wout, ws);
  viterbi_k<<<128, 64, 0, stream>>>(ws + OFF_EF, ws + OFF_EB, bout, trans, masks, out);
}

// Round 12
// 12164.425 us; speedup vs baseline: 1.2185x; 1.0046x over previous
//
#include <hip/hip_runtime.h>
#include <cfloat>
#include <cmath>

#define Bn 128
#define Tn 512
#define En 256
#define Hn 512
#define NTAGS 32
#define CHK 64                   // k-rows per staged chunk
#define NCHK 12                  // 8 h-chunks (512 k) + 4 x-chunks (256 k)

// ws float offsets (h stored [k][b] dense)
#define OFF_HF 0                          // [2][512][128]
#define OFF_HB 131072
#define OFF_CF 262144                     // [512][128]
#define OFF_CB 327680
#define OFF_EF 393216                     // [512][32][128]
#define OFF_EB 2490368
// end 4587520 floats = 17.5 MB

__device__ __forceinline__ void gll16(const float* g, float* l) {
  __builtin_amdgcn_global_load_lds(
      (const __attribute__((address_space(1))) void*)g,
      (__attribute__((address_space(3))) void*)l, 16, 0, 0);
}

__global__ __launch_bounds__(512, 2) void lstm_step_k(
    const float* __restrict__ X, const float* __restrict__ masks,
    const float* __restrict__ Wih_f, const float* __restrict__ Whh_f, const float* __restrict__ bias_f,
    const float* __restrict__ Wih_b, const float* __restrict__ Whh_b, const float* __restrict__ bias_b,
    const float* __restrict__ Wout, float* __restrict__ ws, int s)
{
  __shared__ __align__(16) float WT[768 * 16];      // 48 KB  W [k][c]
  __shared__ __align__(16) float HX[2][CHK * Bn];   // 64 KB  A chunks [k][b] dense
  __shared__ __align__(16) float GL[Bn * 17];       // 8.7 KB gates [b][c]
  __shared__ __align__(16) float WoL[512];          // 2 KB   Wout row (block's tag/dir)
  __shared__ __align__(16) float RS[8 * Bn];        // 4 KB   emission partials [slice][b]

  const int tid  = threadIdx.x;
  const int blk  = blockIdx.x;
  const int lane = tid & 63;
  const int wid  = __builtin_amdgcn_readfirstlane(tid >> 6);  // 0..7 uniform
  const int bq   = tid & 15;         // b-quad pair: bA = bq*4, bB = 64 + bq*4
  const int cg   = (tid >> 4) & 1;   // c half: cols [cg*8, cg*8+8)
  const int ks   = tid >> 5;         // 0..15 k-slice: k in [ks*4, ks*4+4) per chunk

  const int dir = blk >> 7;
  const int bbk = blk & 127;
  const int t = dir ? (Tn - 1 - s) : s;
  const float* Wih  = dir ? Wih_b  : Wih_f;
  const float* Whh  = dir ? Whh_b  : Whh_f;
  const float* bias = dir ? bias_b : bias_f;
  float* hbuf = ws + (dir ? OFF_HB : OFF_HF);
  float* cbuf = ws + (dir ? OFF_CB : OFF_CF);
  const int rbuf = (s + 1) & 1;
  const int wbuf = s & 1;
  const float* hprev = hbuf + rbuf * (Hn * Bn);
  float*       hnext = hbuf + wbuf * (Hn * Bn);
  const int hidx0 = bbk * 4;

  // emission role: (dir, tag); ebq==0 blocks write the full 128-b row
  const int etag = bbk & 31;
  const int ebq  = bbk >> 5;

  // ---- prologue: issue chunk-0 staging (gll16), then stage W + WoL ----
  #pragma unroll
  for (int r = 0; r < 4; ++r) {
    const int item = r * 512 + tid;                // 2048 float4 = 64x128
    gll16(hprev + item * 4, &HX[0][item * 4]);
  }
  {
    const int lc = tid & 15;
    const int kw = tid >> 4;                       // 0..31
    const int row = (lc >> 2) * Hn + hidx0 + (lc & 3);
    #pragma unroll
    for (int i = 0; i < 6; ++i) {
      const int k = (kw + i * 32) * 4;             // 0..764
      float4 w4;
      if (k < Hn) w4 = *(const float4*)&Whh[(size_t)row * Hn + k];
      else        w4 = *(const float4*)&Wih[(size_t)row * En + (k - Hn)];
      WT[(k + 0) * 16 + lc] = w4.x; WT[(k + 1) * 16 + lc] = w4.y;
      WT[(k + 2) * 16 + lc] = w4.z; WT[(k + 3) * 16 + lc] = w4.w;
    }
  }
  if (tid < 128) {
    const float4 wo = *(const float4*)&Wout[(size_t)etag * (2 * Hn) + dir * Hn + tid * 4];
    *(float4*)&WoL[tid * 4] = wo;
  }
  __syncthreads();

  float acc[8][8];
  #pragma unroll
  for (int m = 0; m < 8; ++m)
    #pragma unroll
    for (int n = 0; n < 8; ++n) acc[m][n] = 0.f;
  float eac[8] = {0.f, 0.f, 0.f, 0.f, 0.f, 0.f, 0.f, 0.f};

  const int xbq = tid & 127;                       // for x staging
  const int xeg = tid >> 7;                        // 0..3

  // ---- main loop: 12 chunks of 64 k (c 0..7 = h via gll16, c 8..11 = x via regs) ----
  #pragma unroll 1
  for (int c = 0; c < NCHK; ++c) {
    const int nxt = c + 1;
    float4 st[4];
    if (nxt < 8) {
      const float* src = hprev + nxt * (CHK * Bn);
      float* dst = &HX[nxt & 1][0];
      #pragma unroll
      for (int r = 0; r < 4; ++r) {
        const int item = r * 512 + tid;
        gll16(src + item * 4, dst + item * 4);
      }
    } else if (nxt < NCHK) {
      const int e0 = (nxt - 8) * CHK;
      #pragma unroll
      for (int r = 0; r < 4; ++r)
        st[r] = *(const float4*)&X[(size_t)xbq * (Tn * En) + (size_t)t * En + e0 + xeg * 16 + r * 4];
    }

    // ---- compute chunk c: 8x8 per-lane tile, 4 b128 per 64 FMA ----
    {
      const float* HXc = &HX[c & 1][0];
      #pragma unroll
      for (int j = 0; j < 4; ++j) {
        const int kl = ks * 4 + j;
        const int kg = c * 64 + kl;
        const float4 a0 = *(const float4*)&HXc[kl * Bn + bq * 4];
        const float4 a1 = *(const float4*)&HXc[kl * Bn + 64 + bq * 4];
        const float4 w0 = *(const float4*)&WT[kg * 16 + cg * 8];
        const float4 w1 = *(const float4*)&WT[kg * 16 + cg * 8 + 4];
        const float a_[8] = {a0.x, a0.y, a0.z, a0.w, a1.x, a1.y, a1.z, a1.w};
        const float w_[8] = {w0.x, w0.y, w0.z, w0.w, w1.x, w1.y, w1.z, w1.w};
        #pragma unroll
        for (int m = 0; m < 8; ++m)
          #pragma unroll
          for (int n = 0; n < 8; ++n)
            acc[m][n] += a_[m] * w_[n];
        if (c < 8) {
          const float wo = WoL[kg];
          #pragma unroll
          for (int m = 0; m < 8; ++m) eac[m] += a_[m] * wo;
        }
      }
    }

    // ---- write staged x regs into next buffer ----
    if (nxt >= 8 && nxt < NCHK) {
      float* dst = &HX[nxt & 1][0];
      #pragma unroll
      for (int r = 0; r < 4; ++r) {
        const int el = xeg * 16 + r * 4;
        dst[(el + 0) * Bn + xbq] = st[r].x;
        dst[(el + 1) * Bn + xbq] = st[r].y;
        dst[(el + 2) * Bn + xbq] = st[r].z;
        dst[(el + 3) * Bn + xbq] = st[r].w;
      }
    }
    __syncthreads();
  }

  // ---- fold ks pairs in-register (lane ^ 32), leaving 8 slices = wid ----
  #pragma unroll
  for (int m = 0; m < 8; ++m)
    #pragma unroll
    for (int n = 0; n < 8; ++n)
      acc[m][n] += __shfl_xor(acc[m][n], 32);
  #pragma unroll
  for (int m = 0; m < 8; ++m) eac[m] += __shfl_xor(eac[m], 32);

  // ---- slice reduction via LDS: P[wid][c16][b128] overlaid on HX ----
  float* P = &HX[0][0];                            // 16384 floats
  if ((lane >> 5) == 0) {
    #pragma unroll
    for (int n = 0; n < 8; ++n) {
      *(float4*)&P[wid * 2048 + (cg * 8 + n) * Bn + bq * 4] =
          make_float4(acc[0][n], acc[1][n], acc[2][n], acc[3][n]);
      *(float4*)&P[wid * 2048 + (cg * 8 + n) * Bn + 64 + bq * 4] =
          make_float4(acc[4][n], acc[5][n], acc[6][n], acc[7][n]);
    }
    if (cg == 0) {
      *(float4*)&RS[wid * Bn + bq * 4] = make_float4(eac[0], eac[1], eac[2], eac[3]);
      *(float4*)&RS[wid * Bn + 64 + bq * 4] = make_float4(eac[4], eac[5], eac[6], eac[7]);
    }
  }
  __syncthreads();
  {
    const int b  = tid & 127;
    const int cq = tid >> 7;                       // 0..3
    #pragma unroll
    for (int nn = 0; nn < 4; ++nn) {
      const int n = cq * 4 + nn;
      float v = 0.f;
      #pragma unroll
      for (int k2 = 0; k2 < 8; ++k2)
        v += P[k2 * 2048 + n * Bn + b];
      GL[b * 17 + n] = v;
    }
  }
  // emission finish: full 128-b row for this block's tag (ebq==0 blocks only)
  if (s > 0 && ebq == 0 && tid < 128) {
    const int tprev = dir ? (Tn - s) : (s - 1);
    float* Edst = ws + (dir ? OFF_EB : OFF_EF);
    float v = 0.f;
    #pragma unroll
    for (int g = 0; g < 8; ++g) v += RS[g * Bn + tid];
    Edst[(size_t)tprev * (NTAGS * Bn) + etag * Bn + tid] = v;
  }
  __syncthreads();

  // ---- LSTM pointwise update ----
  {
    const int b  = tid & 127;
    const int hh = tid >> 7;
    const int hidx = hidx0 + hh;
    const float gi = GL[b * 17 + hh]      + bias[hidx];
    const float gf = GL[b * 17 + 4 + hh]  + bias[Hn + hidx];
    const float gc = GL[b * 17 + 8 + hh]  + bias[2 * Hn + hidx];
    const float go = GL[b * 17 + 12 + hh] + bias[3 * Hn + hidx];
    const float iv = 1.f / (1.f + expf(-gi));
    const float fv = 1.f / (1.f + expf(-gf));
    const float gv = tanhf(gc);
    const float ov = 1.f / (1.f + expf(-go));
    const float cold = cbuf[hidx * Bn + b];
    const float cnew = fv * cold + iv * gv;
    const float hold = hprev[hidx * Bn + b];
    const float hnew = ov * tanhf(cnew);
    const float m = masks[(size_t)b * Tn + t];
    hnext[hidx * Bn + b] = (m > 0.f) ? hnew : hold;
    cbuf[hidx * Bn + b]  = (m > 0.f) ? cnew : cold;
  }
}

__global__ __launch_bounds__(512) void emis_final_k(const float* __restrict__ Wout,
                                                    float* __restrict__ ws)
{
  __shared__ float RSf[16 * Bn];
  const int tid = threadIdx.x;
  const int dir = blockIdx.x >> 5;
  const int tag = blockIdx.x & 31;
  // final states: h_f[T-1] and h_b[0] both written at s=511 (wbuf=1)
  const float* hsrc = ws + (dir ? OFF_HB : OFF_HF) + 1 * (Hn * Bn);
  const int tprev = dir ? 0 : (Tn - 1);
  const float* wrow = Wout + (size_t)tag * (2 * Hn) + dir * Hn;
  float* Edst = ws + (dir ? OFF_EB : OFF_EF);
  const int bq = tid & 31;
  const int kg = tid >> 5;
  float4 a4 = make_float4(0.f, 0.f, 0.f, 0.f);
  #pragma unroll 4
  for (int kk = 0; kk < 32; ++kk) {
    const int k = kg * 32 + kk;
    const float w = wrow[k];
    const float4 h4 = *(const float4*)&hsrc[k * Bn + bq * 4];
    a4.x += h4.x * w; a4.y += h4.y * w; a4.z += h4.z * w; a4.w += h4.w * w;
  }
  *(float4*)&RSf[kg * Bn + bq * 4] = a4;
  __syncthreads();
  if (tid < 128) {
    float v = 0.f;
    #pragma unroll
    for (int g = 0; g < 16; ++g) v += RSf[g * Bn + tid];
    Edst[(size_t)tprev * (NTAGS * Bn) + tag * Bn + tid] = v;
  }
}

__global__ __launch_bounds__(64) void viterbi_k(
    const float* __restrict__ Ef, const float* __restrict__ Eb,
    const float* __restrict__ bout, const float* __restrict__ trans,
    const float* __restrict__ masks, float* __restrict__ out)
{
  const int b = blockIdx.x;
  const int l = threadIdx.x;
  __shared__ float tr[32][32];
  __shared__ float al[32];
  __shared__ float msk[512];
  __shared__ unsigned char bp[512][32];
  __shared__ int tseq[512];

  for (int i = l; i < 1024; i += 64) tr[i >> 5][i & 31] = trans[i];
  for (int i = l; i < 512; i += 64) msk[i] = masks[(size_t)b * 512 + i];
  __syncthreads();

  const int j  = l & 31;
  const int hi = l >> 5;
  if (l < 32)
    al[j] = Ef[(size_t)j * Bn + b] + Eb[(size_t)j * Bn + b] + bout[j] + tr[30][j];
  __syncthreads();

  for (int t = 1; t < 512; ++t) {
    float pmax = -FLT_MAX; int pidx = 0;
    #pragma unroll
    for (int ii = 0; ii < 16; ++ii) {
      const int i = hi * 16 + ii;
      const float sc = al[i] + tr[i][j];
      if (sc > pmax) { pmax = sc; pidx = i; }   // strict > => first occurrence
    }
    const float omax = __shfl_down(pmax, 32);
    const int   oidx = __shfl_down(pidx, 32);
    if (l < 32) {
      if (omax > pmax) { pmax = omax; pidx = oidx; } // high half only on strict >
      bp[t][j] = (unsigned char)pidx;
      const float e = Ef[(size_t)t * (NTAGS * Bn) + j * Bn + b]
                    + Eb[(size_t)t * (NTAGS * Bn) + j * Bn + b] + bout[j];
      const float na = pmax + e;
      if (msk[t] > 0.f) al[j] = na;
    }
    __syncthreads();
  }

  float fv; int fidx;
  if (l < 32) { fv = al[l] + tr[l][31]; fidx = l; }
  else        { fv = -FLT_MAX; fidx = 1 << 30; }
  #pragma unroll
  for (int off = 16; off >= 1; off >>= 1) {
    const float v2 = __shfl_xor(fv, off);
    const int   i2 = __shfl_xor(fidx, off);
    if (v2 > fv || (v2 == fv && i2 < fidx)) { fv = v2; fidx = i2; }
  }
  if (l == 0) {
    out[b] = fv;
    int cur = fidx;
    tseq[511] = cur;
    for (int t = 511; t >= 1; --t) {
      const int prev = (msk[t] > 0.f) ? (int)bp[t][cur] : cur;
      tseq[t - 1] = prev;
      cur = prev;
    }
  }
  __syncthreads();
  for (int t = l; t < 512; t += 64) {
    const float tv = (msk[t] > 0.f) ? (float)tseq[t] : -1.0f;
    out[Bn + (size_t)b * 512 + t] = tv;
  }
}

extern "C" void kernel_launch(void* const* d_in, const int* in_sizes, int n_in,
                              void* d_out, int out_size, void* d_ws, size_t ws_size,
                              hipStream_t stream) {
  const float* X      = (const float*)d_in[0];
  const float* masks  = (const float*)d_in[1];
  const float* Wih_f  = (const float*)d_in[3];
  const float* Whh_f  = (const float*)d_in[4];
  const float* bf     = (const float*)d_in[5];
  const float* Wih_b  = (const float*)d_in[6];
  const float* Whh_b  = (const float*)d_in[7];
  const float* bb     = (const float*)d_in[8];
  const float* Wout   = (const float*)d_in[9];
  const float* bout   = (const float*)d_in[10];
  const float* trans  = (const float*)d_in[11];
  float* ws  = (float*)d_ws;
  float* out = (float*)d_out;

  // zero h/c state region (graph replays re-run this)
  hipMemsetAsync(d_ws, 0, (size_t)OFF_EF * sizeof(float), stream);

  for (int s = 0; s < Tn; ++s)
    lstm_step_k<<<256, 512, 0, stream>>>(X, masks, Wih_f, Whh_f, bf,
                                         Wih_b, Whh_b, bb, Wout, ws, s);
  emis_final_k<<<64, 512, 0, stream>>>(Wout, ws);
  viterbi_k<<<128, 64, 0, stream>>>(ws + OFF_EF, ws + OFF_EB, bout, trans, masks, out);
}